// Round 3
// baseline (280.996 us; speedup 1.0000x reference)
//
#include <hip/hip_runtime.h>
#include <stdint.h>

typedef __attribute__((ext_vector_type(4))) float  float4v;
typedef __attribute__((ext_vector_type(8))) __bf16 bf16x8;
typedef __attribute__((ext_vector_type(8))) unsigned short ushort8;

#define B_DIM 8192
#define H_DIM 1024
#define O_DIM 1024

static __device__ __forceinline__ unsigned short f32_to_bf16(float f) {
  union { float f; unsigned int u; } v; v.f = f;
  unsigned int u = v.u;
  unsigned int r = u + 0x7FFFu + ((u >> 16) & 1u);  // round-to-nearest-even
  return (unsigned short)(r >> 16);
}

// ---------------------------------------------------------------------------
// prep_inputs: unchanged (near memory floor; ~10 us incl. harness resets).
// ---------------------------------------------------------------------------
__global__ void prep_inputs(const float* __restrict__ state,
                            const float* __restrict__ basis,
                            const float* __restrict__ prjw,
                            unsigned short* __restrict__ Abf,
                            unsigned short* __restrict__ Wt) {
  __shared__ __align__(16) unsigned short t[64 * 72];
  int bb = blockIdx.x;
  int tid = threadIdx.x;
  if (bb < 1280) {
    int m = bb >> 8, panel = bb & 255;
    int o0 = (panel & 15) * 64, h0 = (panel >> 4) * 64;
    const float* src = (m < 4) ? (basis + (size_t)m * H_DIM * O_DIM) : prjw;  // [H][O]
    int r  = tid >> 4;
    int c4 = (tid & 15) * 4;
#pragma unroll
    for (int p = 0; p < 4; ++p) {
      int h = r + p * 16;
      float4v v = *(const float4v*)(src + (size_t)(h0 + h) * O_DIM + o0 + c4);
      t[(c4 + 0) * 72 + h] = f32_to_bf16(v.x);
      t[(c4 + 1) * 72 + h] = f32_to_bf16(v.y);
      t[(c4 + 2) * 72 + h] = f32_to_bf16(v.z);
      t[(c4 + 3) * 72 + h] = f32_to_bf16(v.w);
    }
    __syncthreads();
#pragma unroll
    for (int i = 0; i < 2; ++i) {
      int C = i * 256 + tid;
      int o = C >> 3, cc = C & 7;
      ushort8 val = *(const ushort8*)(t + o * 72 + cc * 8);
      *(ushort8*)(Wt + ((size_t)m * O_DIM + o0 + o) * H_DIM + h0 + cc * 8) = val;
    }
  } else {
    int i = (bb - 1280) * 256 + tid;  // 8 elems per thread
    float4v v0 = ((const float4v*)state)[i * 2];
    float4v v1 = ((const float4v*)state)[i * 2 + 1];
    ushort8 o;
    o[0] = f32_to_bf16(v0.x); o[1] = f32_to_bf16(v0.y);
    o[2] = f32_to_bf16(v0.z); o[3] = f32_to_bf16(v0.w);
    o[4] = f32_to_bf16(v1.x); o[5] = f32_to_bf16(v1.y);
    o[6] = f32_to_bf16(v1.z); o[7] = f32_to_bf16(v1.w);
    ((ushort8*)Abf)[i] = o;
  }
}

// ---------------------------------------------------------------------------
// R3: faithful m201 8-phase port onto the fused 5-mode GEMM.
//  Tile 256(B) x 64(O); 512 thr = 8 waves (4 row x 2 col), wave-tile 64x32.
//  Half-tile = BK=32 slab (A 16KB + B 20KB = 36KB).  4-half LDS ring (144KB).
//  Per half-tile: 5 phases (one per mode), each
//    {ds_read frags; 0-2 global_load_lds; s_barrier; lgkmcnt(0);
//     setprio(1); 8 MFMA; setprio(0); s_barrier}.
//  vmcnt guard ONCE per half-tile (end, before closing barrier), counted:
//    steady vmcnt(2L) (L=4 A-waves / 5 B-waves) -> h landed, h+1,h+2 in
//    flight; tail vmcnt(L) then vmcnt(0).  Never drains mid-loop.
//  Load duty: waves 0-3 stage A (4 x 1KB), waves 4-7 stage B (5 x 1KB).
//  Chunk swizzle pos = q ^ ((row>>1)&3) on 64B rows (conflict-free b128).
// ---------------------------------------------------------------------------
__global__ __launch_bounds__(512, 2)
void gemm_fused(const unsigned short* __restrict__ A,
                const unsigned short* __restrict__ Wt,
                const float* __restrict__ se, const float* __restrict__ curv,
                const float* __restrict__ gw, const float* __restrict__ gb,
                const float* __restrict__ prjb,
                float* __restrict__ out) {
  // ring slot r at r*36864: [A 256x32 bf16 = 16384B][B 5 x 64x32 = 20480B]
  __shared__ __align__(16) unsigned char smem[152576];
  float* scf = (float*)(smem + 147456);  // 5 x 256 fp32

  const int tid  = threadIdx.x;
  const int lane = tid & 63;
  const int wave = tid >> 6;
  const int row0 = blockIdx.x * 256;
  const int col0 = blockIdx.y * 64;
  const int wrow = (wave >> 1) * 64;   // 0,64,128,192
  const int wcol = (wave & 1) * 32;    // 0 or 32
  const int q  = lane >> 4;
  const int ln = lane & 15;

  // ---- staging descriptors.  1KB wave-chunk = 16 rows x 32k bf16.
  //      lane l -> row = c*16 + (l>>2), pos = l&3; stored pos holds global
  //      16B-chunk g = pos ^ ((row>>1)&3)  (swizzle).  Pointers are bumped
  //      by 32 elems after each half-tile's issues.
  const unsigned short* gsrc[5];
  unsigned int ldsoff[5];
  if (wave < 4) {
#pragma unroll
    for (int j = 0; j < 4; ++j) {
      int c = wave * 4 + j;                 // A chunk 0..15
      int row = c * 16 + (lane >> 2);
      int pos = lane & 3;
      int g = pos ^ ((row >> 1) & 3);
      gsrc[j] = A + (size_t)(row0 + row) * H_DIM + g * 8;
      ldsoff[j] = c * 1024;
    }
    gsrc[4] = gsrc[0]; ldsoff[4] = ldsoff[0];  // never issued for A-waves
  } else {
#pragma unroll
    for (int j = 0; j < 5; ++j) {
      int c = (wave - 4) * 5 + j;           // B chunk 0..19
      int m = c >> 2;                       // mode (4 chunks per mode)
      int r = (c & 3) * 16 + (lane >> 2);   // row within mode slab (0..63)
      int pos = lane & 3;
      int g = pos ^ ((r >> 1) & 3);
      gsrc[j] = Wt + (size_t)m * O_DIM * H_DIM + (size_t)(col0 + r) * H_DIM + g * 8;
      ldsoff[j] = 16384 + c * 1024;
    }
  }

  // ---- per-wave fragment byte offsets (ushort units), loop-invariant
  int aoffs[4];
#pragma unroll
  for (int t = 0; t < 4; ++t) {
    int ra = wrow + t * 16 + ln;
    aoffs[t] = ra * 32 + (q ^ ((ra >> 1) & 3)) * 8;
  }
  int boffs[2];
  {
    int rb = wcol + ln;      boffs[0] = rb * 32 + (q ^ ((rb >> 1) & 3)) * 8;
    int r1 = wcol + 16 + ln; boffs[1] = r1 * 32 + (q ^ ((r1 >> 1) & 3)) * 8;
  }

  float4v acc[5][4][2];
#pragma unroll
  for (int m = 0; m < 5; ++m)
#pragma unroll
    for (int i = 0; i < 4; ++i)
#pragma unroll
      for (int j = 0; j < 2; ++j)
        acc[m][i][j] = (float4v){0.f, 0.f, 0.f, 0.f};

#define GLDS(j_)                                                                \
  __builtin_amdgcn_global_load_lds(                                             \
      (const __attribute__((address_space(1))) void*)(gsrc[j_]),                \
      (__attribute__((address_space(3))) void*)(dst + ldsoff[j_]), 16, 0, 0)

#define ISSUE_HALF(slot)                                                        \
  do {                                                                          \
    unsigned char* dst = smem + (slot) * 36864;                                 \
    GLDS(0); GLDS(1); GLDS(2); GLDS(3);                                         \
    if (wave >= 4) GLDS(4);                                                     \
    _Pragma("unroll") for (int _j = 0; _j < 5; ++_j) gsrc[_j] += 32;            \
  } while (0)

#define GUARD_2L                                                                \
  do { if (wave < 4) asm volatile("s_waitcnt vmcnt(8)" ::: "memory");           \
       else          asm volatile("s_waitcnt vmcnt(10)" ::: "memory"); } while (0)
#define GUARD_1L                                                                \
  do { if (wave < 4) asm volatile("s_waitcnt vmcnt(4)" ::: "memory");           \
       else          asm volatile("s_waitcnt vmcnt(5)" ::: "memory"); } while (0)
#define GUARD_0   asm volatile("s_waitcnt vmcnt(0)" ::: "memory")
#define GUARD_NONE do { } while (0)

#define MFMA8(m_)                                                               \
  do {                                                                          \
    acc[m_][0][0] = __builtin_amdgcn_mfma_f32_16x16x32_bf16(af0, b0, acc[m_][0][0], 0, 0, 0); \
    acc[m_][1][0] = __builtin_amdgcn_mfma_f32_16x16x32_bf16(af1, b0, acc[m_][1][0], 0, 0, 0); \
    acc[m_][2][0] = __builtin_amdgcn_mfma_f32_16x16x32_bf16(af2, b0, acc[m_][2][0], 0, 0, 0); \
    acc[m_][3][0] = __builtin_amdgcn_mfma_f32_16x16x32_bf16(af3, b0, acc[m_][3][0], 0, 0, 0); \
    acc[m_][0][1] = __builtin_amdgcn_mfma_f32_16x16x32_bf16(af0, b1, acc[m_][0][1], 0, 0, 0); \
    acc[m_][1][1] = __builtin_amdgcn_mfma_f32_16x16x32_bf16(af1, b1, acc[m_][1][1], 0, 0, 0); \
    acc[m_][2][1] = __builtin_amdgcn_mfma_f32_16x16x32_bf16(af2, b1, acc[m_][2][1], 0, 0, 0); \
    acc[m_][3][1] = __builtin_amdgcn_mfma_f32_16x16x32_bf16(af3, b1, acc[m_][3][1], 0, 0, 0); \
  } while (0)

#define PH_BAR_MFMA(m_)                                                         \
  do {                                                                          \
    __builtin_amdgcn_s_barrier();                                               \
    asm volatile("s_waitcnt lgkmcnt(0)" ::: "memory");                          \
    __builtin_amdgcn_s_setprio(1);                                              \
    MFMA8(m_);                                                                  \
    __builtin_amdgcn_s_setprio(0);                                              \
  } while (0)

#define HALF_TILE(hh, DO_GLDS, GUARD)                                           \
  do {                                                                          \
    const unsigned short* sA = (const unsigned short*)(smem + ((hh) & 3) * 36864);\
    const unsigned short* sB = sA + 8192;                                       \
    unsigned char* dst = smem + (((hh) + 3) & 3) * 36864; (void)dst;            \
    /* ph0: A frags + mode0 frags; 2 glds */                                    \
    bf16x8 af0 = *(const bf16x8*)(sA + aoffs[0]);                               \
    bf16x8 af1 = *(const bf16x8*)(sA + aoffs[1]);                               \
    bf16x8 af2 = *(const bf16x8*)(sA + aoffs[2]);                               \
    bf16x8 af3 = *(const bf16x8*)(sA + aoffs[3]);                               \
    bf16x8 b0 = *(const bf16x8*)(sB + boffs[0]);                                \
    bf16x8 b1 = *(const bf16x8*)(sB + boffs[1]);                                \
    if (DO_GLDS) { GLDS(0); GLDS(1); }                                          \
    PH_BAR_MFMA(0);                                                             \
    __builtin_amdgcn_s_barrier();                                               \
    /* ph1: mode1 frags; 2 glds */                                              \
    b0 = *(const bf16x8*)(sB + 2048 + boffs[0]);                                \
    b1 = *(const bf16x8*)(sB + 2048 + boffs[1]);                                \
    if (DO_GLDS) { GLDS(2); GLDS(3); }                                          \
    PH_BAR_MFMA(1);                                                             \
    __builtin_amdgcn_s_barrier();                                               \
    /* ph2: mode2 frags; last glds + pointer bump */                            \
    b0 = *(const bf16x8*)(sB + 4096 + boffs[0]);                                \
    b1 = *(const bf16x8*)(sB + 4096 + boffs[1]);                                \
    if (DO_GLDS) {                                                              \
      if (wave >= 4) GLDS(4);                                                   \
      _Pragma("unroll") for (int _j = 0; _j < 5; ++_j) gsrc[_j] += 32;          \
    }                                                                           \
    PH_BAR_MFMA(2);                                                             \
    __builtin_amdgcn_s_barrier();                                               \
    /* ph3: mode3 frags */                                                      \
    b0 = *(const bf16x8*)(sB + 6144 + boffs[0]);                                \
    b1 = *(const bf16x8*)(sB + 6144 + boffs[1]);                                \
    PH_BAR_MFMA(3);                                                             \
    __builtin_amdgcn_s_barrier();                                               \
    /* ph4: mode4 frags; end-of-half vmcnt guard for next half */               \
    b0 = *(const bf16x8*)(sB + 8192 + boffs[0]);                                \
    b1 = *(const bf16x8*)(sB + 8192 + boffs[1]);                                \
    PH_BAR_MFMA(4);                                                             \
    GUARD;                                                                      \
    __builtin_amdgcn_s_barrier();                                               \
  } while (0)

  // ---- prologue: fill 3 half-tiles of the 4-slot ring, coeff prep overlaps
  ISSUE_HALF(0); ISSUE_HALF(1); ISSUE_HALF(2);
  if (tid < 256) {
    int b = row0 + tid;
    float s = se[b];
    float l0 = fmaf(s, gw[0], gb[0]);
    float l1 = fmaf(s, gw[1], gb[1]);
    float l2 = fmaf(s, gw[2], gb[2]);
    float l3 = fmaf(s, gw[3], gb[3]);
    float mx = fmaxf(fmaxf(l0, l1), fmaxf(l2, l3));
    float e0 = __expf(l0 - mx), e1 = __expf(l1 - mx);
    float e2 = __expf(l2 - mx), e3 = __expf(l3 - mx);
    float mix = 1.0f / (1.0f + __expf(-curv[b]));
    float inv = mix / (e0 + e1 + e2 + e3);
    scf[0 * 256 + tid] = e0 * inv;
    scf[1 * 256 + tid] = e1 * inv;
    scf[2 * 256 + tid] = e2 * inv;
    scf[3 * 256 + tid] = e3 * inv;
    scf[4 * 256 + tid] = 1.0f - mix;
  }
  asm volatile("s_waitcnt lgkmcnt(0)" ::: "memory");  // scf ds_writes retired
  GUARD_2L;                                           // half 0 landed (own wave)
  __builtin_amdgcn_s_barrier();                       // all waves: half 0 ready

  // ---- main loop: 32 half-tiles; issue h+3 spread across h's phases
  for (int h = 0; h < 28; h += 4) {
    HALF_TILE(h + 0, true, GUARD_2L);
    HALF_TILE(h + 1, true, GUARD_2L);
    HALF_TILE(h + 2, true, GUARD_2L);
    HALF_TILE(h + 3, true, GUARD_2L);
  }
  HALF_TILE(28, true,  GUARD_2L);   // issues half 31 (last)
  HALF_TILE(29, false, GUARD_1L);   // ensure half 30 landed
  HALF_TILE(30, false, GUARD_0);    // ensure half 31 landed
  HALF_TILE(31, false, GUARD_NONE);

  // ---- epilogue: mode-combine -> LDS repack (fp32, pitch 68) -> float4 stores
  __syncthreads();
  float* fbuf = (float*)smem;  // 256 x 68 fp32 = 69632 B (scf at 147456 safe)
#pragma unroll
  for (int ti = 0; ti < 4; ++ti) {
    int rl = wrow + ti * 16 + q * 4;
#pragma unroll
    for (int tj = 0; tj < 2; ++tj) {
      int cc = wcol + tj * 16 + ln;
#pragma unroll
      for (int r = 0; r < 4; ++r) {
        float v = 0.f;
#pragma unroll
        for (int m = 0; m < 5; ++m)
          v += scf[m * 256 + rl + r] * acc[m][ti][tj][r];
        fbuf[(rl + r) * 68 + cc] = v;
      }
    }
  }
  __syncthreads();
#pragma unroll
  for (int i = 0; i < 8; ++i) {
    int L = i * 512 + tid;          // 4096 float4s = 256 rows x 16
    int row = L >> 4, c4 = L & 15;
    float4v v = *(const float4v*)(fbuf + row * 68 + c4 * 4);
    float cb = scf[4 * 256 + row];
    float4v pb = *(const float4v*)(prjb + col0 + c4 * 4);
    v += cb * pb;
    *(float4v*)(out + (size_t)(row0 + row) * O_DIM + col0 + c4 * 4) = v;
  }
#undef GLDS
#undef ISSUE_HALF
#undef GUARD_2L
#undef GUARD_1L
#undef GUARD_0
#undef GUARD_NONE
#undef MFMA8
#undef PH_BAR_MFMA
#undef HALF_TILE
}

// ---------------------------------------------------------------------------
extern "C" void kernel_launch(void* const* d_in, const int* in_sizes, int n_in,
                              void* d_out, int out_size, void* d_ws, size_t ws_size,
                              hipStream_t stream) {
  const float* state = (const float*)d_in[0];
  const float* se    = (const float*)d_in[1];
  const float* curv  = (const float*)d_in[2];
  const float* basis = (const float*)d_in[3];
  const float* gw    = (const float*)d_in[4];
  const float* gb    = (const float*)d_in[5];
  const float* prjw  = (const float*)d_in[6];
  const float* prjb  = (const float*)d_in[7];
  float* out = (float*)d_out;

  char* ws = (char*)d_ws;
  unsigned short* Abf = (unsigned short*)ws;                               // 16 MB
  unsigned short* Wt  = (unsigned short*)(ws + (size_t)16 * 1024 * 1024);  // 10 MB

  prep_inputs<<<5376, 256, 0, stream>>>(state, basis, prjw, Abf, Wt);
  dim3 gg(B_DIM / 256, O_DIM / 64);
  gemm_fused<<<gg, 512, 0, stream>>>(Abf, Wt, se, curv, gw, gb, prjb, out);
}

// Round 5
// 179.914 us; speedup vs baseline: 1.5618x; 1.5618x over previous
//
#include <hip/hip_runtime.h>
#include <stdint.h>

typedef __attribute__((ext_vector_type(4))) float  float4v;
typedef __attribute__((ext_vector_type(8))) __bf16 bf16x8;
typedef __attribute__((ext_vector_type(8))) unsigned short ushort8;

#define B_DIM 8192
#define H_DIM 1024
#define O_DIM 1024

static __device__ __forceinline__ unsigned short f32_to_bf16(float f) {
  union { float f; unsigned int u; } v; v.f = f;
  unsigned int u = v.u;
  unsigned int r = u + 0x7FFFu + ((u >> 16) & 1u);  // round-to-nearest-even
  return (unsigned short)(r >> 16);
}

// ---------------------------------------------------------------------------
// prep_inputs: unchanged (near memory floor).
// ---------------------------------------------------------------------------
__global__ void prep_inputs(const float* __restrict__ state,
                            const float* __restrict__ basis,
                            const float* __restrict__ prjw,
                            unsigned short* __restrict__ Abf,
                            unsigned short* __restrict__ Wt) {
  __shared__ __align__(16) unsigned short t[64 * 72];
  int bb = blockIdx.x;
  int tid = threadIdx.x;
  if (bb < 1280) {
    int m = bb >> 8, panel = bb & 255;
    int o0 = (panel & 15) * 64, h0 = (panel >> 4) * 64;
    const float* src = (m < 4) ? (basis + (size_t)m * H_DIM * O_DIM) : prjw;  // [H][O]
    int r  = tid >> 4;
    int c4 = (tid & 15) * 4;
#pragma unroll
    for (int p = 0; p < 4; ++p) {
      int h = r + p * 16;
      float4v v = *(const float4v*)(src + (size_t)(h0 + h) * O_DIM + o0 + c4);
      t[(c4 + 0) * 72 + h] = f32_to_bf16(v.x);
      t[(c4 + 1) * 72 + h] = f32_to_bf16(v.y);
      t[(c4 + 2) * 72 + h] = f32_to_bf16(v.z);
      t[(c4 + 3) * 72 + h] = f32_to_bf16(v.w);
    }
    __syncthreads();
#pragma unroll
    for (int i = 0; i < 2; ++i) {
      int C = i * 256 + tid;
      int o = C >> 3, cc = C & 7;
      ushort8 val = *(const ushort8*)(t + o * 72 + cc * 8);
      *(ushort8*)(Wt + ((size_t)m * O_DIM + o0 + o) * H_DIM + h0 + cc * 8) = val;
    }
  } else {
    int i = (bb - 1280) * 256 + tid;  // 8 elems per thread
    float4v v0 = ((const float4v*)state)[i * 2];
    float4v v1 = ((const float4v*)state)[i * 2 + 1];
    ushort8 o;
    o[0] = f32_to_bf16(v0.x); o[1] = f32_to_bf16(v0.y);
    o[2] = f32_to_bf16(v0.z); o[3] = f32_to_bf16(v0.w);
    o[4] = f32_to_bf16(v1.x); o[5] = f32_to_bf16(v1.y);
    o[6] = f32_to_bf16(v1.z); o[7] = f32_to_bf16(v1.w);
    ((ushort8*)Abf)[i] = o;
  }
}

// ---------------------------------------------------------------------------
// R4: R1 topology (proven 88us: 128x64 tile, 4 waves, 2-ring 2 blocks/CU,
//  one __syncthreads drain/stage) + m201-style intra-stage read-ahead:
//   - ph0 frags (A x4, modes 0,1 B x4) are read at the BOTTOM of the previous
//     stage (right after the drain) and carried in registers across it.
//   - stage body: ISSUE s+1 -> ds_read ph1 frags (modes 2-4) -> 16 MFMA (ph0)
//     -> 24 MFMA (ph1) -> drain -> read next ph0 frags.
//   LDS-read pipe (1344 cyc/stage) hides under the matrix pipe (1552) instead
//   of serializing with it.  setprio wraps MFMA clusters only (T5).
// ---------------------------------------------------------------------------
__global__ __launch_bounds__(256, 2)
void gemm_fused(const unsigned short* __restrict__ A,
                const unsigned short* __restrict__ Wt,
                const float* __restrict__ se, const float* __restrict__ curv,
                const float* __restrict__ gw, const float* __restrict__ gb,
                const float* __restrict__ prjb,
                float* __restrict__ out) {
  __shared__ __align__(16) unsigned char smem[59904];
  // stage buf s&1 at s*28672: [A 128x32 bf16 = 8192B][B 5 x 64x32 = 20480B]
  float* scf = (float*)(smem + 57344);  // 5 x 128 fp32

  const int tid  = threadIdx.x;
  const int lane = tid & 63;
  const int wave = tid >> 6;
  const int row0 = blockIdx.x * 128;
  const int col0 = blockIdx.y * 64;
  const int wrow = (wave >> 1) * 64;   // 0 or 64
  const int wcol = (wave & 1) * 32;    // 0 or 32
  const int q  = lane >> 4;
  const int ln = lane & 15;

  // ---- fused coeff prep: coeff[m][row] for this block's 128 rows
  if (tid < 128) {
    int b = row0 + tid;
    float s = se[b];
    float l0 = fmaf(s, gw[0], gb[0]);
    float l1 = fmaf(s, gw[1], gb[1]);
    float l2 = fmaf(s, gw[2], gb[2]);
    float l3 = fmaf(s, gw[3], gb[3]);
    float mx = fmaxf(fmaxf(l0, l1), fmaxf(l2, l3));
    float e0 = __expf(l0 - mx), e1 = __expf(l1 - mx);
    float e2 = __expf(l2 - mx), e3 = __expf(l3 - mx);
    float mix = 1.0f / (1.0f + __expf(-curv[b]));
    float inv = mix / (e0 + e1 + e2 + e3);
    scf[0 * 128 + tid] = e0 * inv;
    scf[1 * 128 + tid] = e1 * inv;
    scf[2 * 128 + tid] = e2 * inv;
    scf[3 * 128 + tid] = e3 * inv;
    scf[4 * 128 + tid] = 1.0f - mix;
  }

  // ---- staging descriptors (16B chunks; stored pos holds global chunk
  //      g = pos ^ ((row>>1)&3); rows are 32 elems = 64B = 4 chunks)
  const unsigned short* gA[2];
  unsigned int ldsA[2];
#pragma unroll
  for (int j = 0; j < 2; ++j) {
    int C = (wave * 2 + j) * 64 + lane;     // 0..511
    int row = C >> 2, pos = C & 3;
    int g = pos ^ ((row >> 1) & 3);
    gA[j] = A + (size_t)(row0 + row) * H_DIM + g * 8;
    ldsA[j] = (wave * 2 + j) * 1024;        // wave-uniform base (HW adds lane*16)
  }
  const unsigned short* gB[5];
  unsigned int ldsBbase = 8192 + wave * 1024;
  {
    int C = wave * 64 + lane;               // 0..255
    int row = C >> 2, pos = C & 3;
    int g = pos ^ ((row >> 1) & 3);
#pragma unroll
    for (int m = 0; m < 5; ++m)
      gB[m] = Wt + (size_t)m * O_DIM * H_DIM + (size_t)(col0 + row) * H_DIM + g * 8;
  }

  // ---- loop-invariant fragment offsets (ushort units; row = 32 ushorts)
  int aoffs[4];
#pragma unroll
  for (int t = 0; t < 4; ++t) {
    int ra = wrow + t * 16 + ln;
    aoffs[t] = ra * 32 + (q ^ ((ra >> 1) & 3)) * 8;
  }
  int boffs[2];
  {
    int rb = wcol + ln;      boffs[0] = rb * 32 + (q ^ ((rb >> 1) & 3)) * 8;
    int r1 = wcol + 16 + ln; boffs[1] = r1 * 32 + (q ^ ((r1 >> 1) & 3)) * 8;
  }

  float4v acc[5][4][2];
#pragma unroll
  for (int m = 0; m < 5; ++m)
#pragma unroll
    for (int i = 0; i < 4; ++i)
#pragma unroll
      for (int j = 0; j < 2; ++j)
        acc[m][i][j] = (float4v){0.f, 0.f, 0.f, 0.f};

#define ISSUE_STAGE(s)                                                          \
  do {                                                                          \
    const int _buf = (s) & 1;                                                   \
    const int _k = (s) * 32;                                                    \
    unsigned char* _base = smem + _buf * 28672;                                 \
    _Pragma("unroll")                                                           \
    for (int _j = 0; _j < 2; ++_j)                                              \
      __builtin_amdgcn_global_load_lds(                                         \
          (const __attribute__((address_space(1))) void*)(gA[_j] + _k),         \
          (__attribute__((address_space(3))) void*)(_base + ldsA[_j]), 16, 0, 0);\
    _Pragma("unroll")                                                           \
    for (int _m = 0; _m < 5; ++_m)                                              \
      __builtin_amdgcn_global_load_lds(                                         \
          (const __attribute__((address_space(1))) void*)(gB[_m] + _k),         \
          (__attribute__((address_space(3))) void*)(_base + ldsBbase + _m * 4096),\
          16, 0, 0);                                                            \
  } while (0)

  // persistent ph0 fragments (carried across the drain barrier)
  bf16x8 a0, a1, a2, a3, b00, b01, b10, b11;

#define READ_PH0(buf)                                                           \
  do {                                                                          \
    const unsigned short* _sA = (const unsigned short*)(smem + (buf) * 28672);  \
    const unsigned short* _sB = _sA + 4096;                                     \
    a0 = *(const bf16x8*)(_sA + aoffs[0]);                                      \
    a1 = *(const bf16x8*)(_sA + aoffs[1]);                                      \
    a2 = *(const bf16x8*)(_sA + aoffs[2]);                                      \
    a3 = *(const bf16x8*)(_sA + aoffs[3]);                                      \
    b00 = *(const bf16x8*)(_sB + boffs[0]);                                     \
    b01 = *(const bf16x8*)(_sB + boffs[1]);                                     \
    b10 = *(const bf16x8*)(_sB + 2048 + boffs[0]);                              \
    b11 = *(const bf16x8*)(_sB + 2048 + boffs[1]);                              \
  } while (0)

#define MFMA_MODE(m_, bb0, bb1)                                                 \
  do {                                                                          \
    acc[m_][0][0] = __builtin_amdgcn_mfma_f32_16x16x32_bf16(a0, bb0, acc[m_][0][0], 0, 0, 0); \
    acc[m_][1][0] = __builtin_amdgcn_mfma_f32_16x16x32_bf16(a1, bb0, acc[m_][1][0], 0, 0, 0); \
    acc[m_][2][0] = __builtin_amdgcn_mfma_f32_16x16x32_bf16(a2, bb0, acc[m_][2][0], 0, 0, 0); \
    acc[m_][3][0] = __builtin_amdgcn_mfma_f32_16x16x32_bf16(a3, bb0, acc[m_][3][0], 0, 0, 0); \
    acc[m_][0][1] = __builtin_amdgcn_mfma_f32_16x16x32_bf16(a0, bb1, acc[m_][0][1], 0, 0, 0); \
    acc[m_][1][1] = __builtin_amdgcn_mfma_f32_16x16x32_bf16(a1, bb1, acc[m_][1][1], 0, 0, 0); \
    acc[m_][2][1] = __builtin_amdgcn_mfma_f32_16x16x32_bf16(a2, bb1, acc[m_][2][1], 0, 0, 0); \
    acc[m_][3][1] = __builtin_amdgcn_mfma_f32_16x16x32_bf16(a3, bb1, acc[m_][3][1], 0, 0, 0); \
  } while (0)

  ISSUE_STAGE(0);
  __syncthreads();   // stage 0 landed (compiler drains vmcnt); scf visible
  READ_PH0(0);       // ph0 frags of stage 0 into registers

#pragma unroll 2
  for (int s = 0; s < 31; ++s) {
    ISSUE_STAGE(s + 1);   // prefetch into the other buffer
    // ph1 fragment reads (modes 2,3,4) — issue before any MFMA so they
    // overlap the ph0 MFMA cluster below (compiler emits counted lgkmcnt).
    const unsigned short* cB =
        (const unsigned short*)(smem + (s & 1) * 28672) + 4096;
    bf16x8 c20 = *(const bf16x8*)(cB + 2 * 2048 + boffs[0]);
    bf16x8 c21 = *(const bf16x8*)(cB + 2 * 2048 + boffs[1]);
    bf16x8 c30 = *(const bf16x8*)(cB + 3 * 2048 + boffs[0]);
    bf16x8 c31 = *(const bf16x8*)(cB + 3 * 2048 + boffs[1]);
    bf16x8 c40 = *(const bf16x8*)(cB + 4 * 2048 + boffs[0]);
    bf16x8 c41 = *(const bf16x8*)(cB + 4 * 2048 + boffs[1]);
    // ph0 MFMA: operands already in registers since last iteration
    __builtin_amdgcn_s_setprio(1);
    MFMA_MODE(0, b00, b01);
    MFMA_MODE(1, b10, b11);
    __builtin_amdgcn_s_setprio(0);
    // ph1 MFMA: waits only on the 6 reads above (FIFO lgkmcnt)
    __builtin_amdgcn_s_setprio(1);
    MFMA_MODE(2, c20, c21);
    MFMA_MODE(3, c30, c31);
    MFMA_MODE(4, c40, c41);
    __builtin_amdgcn_s_setprio(0);
    __syncthreads();      // drain s+1 loads + all waves done reading buf s
    READ_PH0((s + 1) & 1);
  }
  // ---- final stage 31: ph1 reads + full 40-MFMA compute
  {
    const unsigned short* cB =
        (const unsigned short*)(smem + (31 & 1) * 28672) + 4096;
    bf16x8 c20 = *(const bf16x8*)(cB + 2 * 2048 + boffs[0]);
    bf16x8 c21 = *(const bf16x8*)(cB + 2 * 2048 + boffs[1]);
    bf16x8 c30 = *(const bf16x8*)(cB + 3 * 2048 + boffs[0]);
    bf16x8 c31 = *(const bf16x8*)(cB + 3 * 2048 + boffs[1]);
    bf16x8 c40 = *(const bf16x8*)(cB + 4 * 2048 + boffs[0]);
    bf16x8 c41 = *(const bf16x8*)(cB + 4 * 2048 + boffs[1]);
    __builtin_amdgcn_s_setprio(1);
    MFMA_MODE(0, b00, b01);
    MFMA_MODE(1, b10, b11);
    MFMA_MODE(2, c20, c21);
    MFMA_MODE(3, c30, c31);
    MFMA_MODE(4, c40, c41);
    __builtin_amdgcn_s_setprio(0);
  }

  // ---- epilogue: mode-combine -> LDS repack (fp32, pitch 68) -> float4 stores
  __syncthreads();
  float* fbuf = (float*)smem;  // 128 x 68 fp32 = 34816 B (scf at 57344 safe)
#pragma unroll
  for (int ti = 0; ti < 4; ++ti) {
    int rl = wrow + ti * 16 + q * 4;
#pragma unroll
    for (int tj = 0; tj < 2; ++tj) {
      int cc = wcol + tj * 16 + ln;
#pragma unroll
      for (int r = 0; r < 4; ++r) {
        float v = 0.f;
#pragma unroll
        for (int m = 0; m < 5; ++m)
          v += scf[m * 128 + rl + r] * acc[m][ti][tj][r];
        fbuf[(rl + r) * 68 + cc] = v;
      }
    }
  }
  __syncthreads();
#pragma unroll
  for (int i = 0; i < 8; ++i) {
    int L = i * 256 + tid;          // 2048 float4s = 128 rows x 16
    int row = L >> 4, c4 = L & 15;
    float4v v = *(const float4v*)(fbuf + row * 68 + c4 * 4);
    float cb = scf[4 * 128 + row];
    float4v pb = *(const float4v*)(prjb + col0 + c4 * 4);
    v += cb * pb;
    *(float4v*)(out + (size_t)(row0 + row) * O_DIM + col0 + c4 * 4) = v;
  }
#undef ISSUE_STAGE
#undef READ_PH0
#undef MFMA_MODE
}

// ---------------------------------------------------------------------------
extern "C" void kernel_launch(void* const* d_in, const int* in_sizes, int n_in,
                              void* d_out, int out_size, void* d_ws, size_t ws_size,
                              hipStream_t stream) {
  const float* state = (const float*)d_in[0];
  const float* se    = (const float*)d_in[1];
  const float* curv  = (const float*)d_in[2];
  const float* basis = (const float*)d_in[3];
  const float* gw    = (const float*)d_in[4];
  const float* gb    = (const float*)d_in[5];
  const float* prjw  = (const float*)d_in[6];
  const float* prjb  = (const float*)d_in[7];
  float* out = (float*)d_out;

  char* ws = (char*)d_ws;
  unsigned short* Abf = (unsigned short*)ws;                               // 16 MB
  unsigned short* Wt  = (unsigned short*)(ws + (size_t)16 * 1024 * 1024);  // 10 MB

  prep_inputs<<<5376, 256, 0, stream>>>(state, basis, prjw, Abf, Wt);
  dim3 gg(B_DIM / 128, O_DIM / 64);
  gemm_fused<<<gg, 256, 0, stream>>>(Abf, Wt, se, curv, gw, gb, prjb, out);
}